// Round 1
// 556.292 us; speedup vs baseline: 1.0461x; 1.0461x over previous
//
#include <hip/hip_runtime.h>
#include <math.h>

// ---- problem constants ----
#define BB 16
#define CIN 256
#define MM 4096      // H*W
#define HIDC 256
#define NQ 300
#define NHH 4
#define HDD 16

// ---- output offsets (floats) ----
#define OFF_BOXES  0
#define OFF_SCORES 19200
#define OFF_CLS    24000
#define OFF_MAPS   408000
#define OFF_DIV    20068800
#define OFF_SF     20068801

// ---- workspace offsets (in floats) ----
#define WS_COMB16  0            // 16*256*4096 ushort
#define WS_KEYS16  8388608      // keysT: (b, m=4096, d=64) bf16  (transposed layout!)
#define WS_ATTN16  10485760     // 16*300*4096 ushort
#define WS_T32     20316160     // 16*300*256 fp32
#define WS_T16     21544960     // 16*300*256 ushort
#define WS_VALW16  22159360     // 65536 ushort
#define WS_SUMS    22192128     // 16*4*300 fp32 (exp-sum per b,h,n; atomically accumulated)
#define WS_NORM    22211328     // 4800 floats: SUM OF SQUARES per (b,n) (sqrt taken in simdiv)
#define WS_ACC     22216128     // 1 float (+pad)
#define WS_P       22216192     // head scratch base (P buffer eliminated — no stored-P path)

// head scratch (was P-alias region; P no longer exists)
#define HP_SF16   (WS_P + 0)         // 4800x256 bf16  (614400 fl)
#define HP_Z1PRE  (WS_P + 614400)    // 4800x256 fp32  (1228800 fl)
#define HP_Z1_16  (WS_P + 1843200)   // 4800x256 bf16  (614400 fl)
#define HP_Z2BB   (WS_P + 2457600)   // 4800x128 bf16  (307200 fl)
#define HP_Z2CH   (WS_P + 2764800)   // 4800x128 bf16  (307200 fl)
#define HP_HW     (WS_P + 3072000)   // head weights bf16 (~108.6k fl)
#define WS_Q16    (WS_P + 3200000)   // 320x64 bf16 q (0.25-scaled, rows 300..319 zero) = 10240 fl
// total ws requirement ≈ (WS_Q16 + 10240) * 4 B ≈ 102 MB (harness provides ≥246 MB)

// ushort offsets within HP_HW:
#define HW_BB1 0
#define HW_CH1 65536
#define HW_BB2 131072
#define HW_CH2 163840
#define HW_CTP 196608

typedef short short8 __attribute__((ext_vector_type(8)));
typedef float floatx4 __attribute__((ext_vector_type(4)));

__device__ __forceinline__ unsigned short f2bf(float f){
  unsigned int u = __float_as_uint(f);
  u = (u + 0x7FFFu + ((u >> 16) & 1u)) >> 16;
  return (unsigned short)u;
}
__device__ __forceinline__ float bf1(unsigned short u){
  return __uint_as_float((unsigned int)u << 16);
}
__device__ __forceinline__ float4 ld_bf4(const unsigned short* p){
  ushort4 u = *(const ushort4*)p;
  float4 f;
  f.x = bf1(u.x); f.y = bf1(u.y); f.z = bf1(u.z); f.w = bf1(u.w);
  return f;
}

__global__ void zero_kernel(float* p){ p[0] = 0.f; }

__global__ __launch_bounds__(256) void zero4_kernel(float4* __restrict__ p, int n4){
  int i = blockIdx.x * 256 + threadIdx.x;
  if (i < n4) p[i] = make_float4(0.f, 0.f, 0.f, 0.f);
}

__global__ __launch_bounds__(256) void cast4_bf16_kernel(const float* __restrict__ src,
                                                         unsigned short* __restrict__ dst, int n4){
  int i = blockIdx.x * 256 + threadIdx.x;
  if (i < n4){
    float4 v = ((const float4*)src)[i];
    ushort4 u;
    u.x = f2bf(v.x); u.y = f2bf(v.y); u.z = f2bf(v.z); u.w = f2bf(v.w);
    ((ushort4*)dst)[i] = u;
  }
}

// q16[n][d] = bf16(ss[n][d] * 0.25), zero-padded to 320 rows for clamp-free MFMA A-frags
__global__ __launch_bounds__(256) void castq_kernel(const float* __restrict__ ss,
                                                    unsigned short* __restrict__ q16){
  int i = blockIdx.x * 256 + threadIdx.x;
  if (i < 320*64)
    q16[i] = (i < NQ*64) ? f2bf(ss[i] * 0.25f) : (unsigned short)0;
}

// one fused cast of all bf16 weight copies
__global__ __launch_bounds__(256) void cast_heads_kernel(
    const float* __restrict__ val_w, const float* __restrict__ bb1_w,
    const float* __restrict__ ch1_w, const float* __restrict__ bb2_w,
    const float* __restrict__ ch2_w, const float* __restrict__ ctp_w,
    unsigned short* __restrict__ valw16, unsigned short* __restrict__ hw16){
  int i = blockIdx.x * 256 + threadIdx.x;
  int T = gridDim.x * 256;
  for (int j = i; j < 65536; j += T) valw16[j] = f2bf(val_w[j]);
  for (int j = i; j < 65536; j += T) hw16[HW_BB1 + j] = f2bf(bb1_w[j]);
  for (int j = i; j < 65536; j += T) hw16[HW_CH1 + j] = f2bf(ch1_w[j]);
  for (int j = i; j < 32768; j += T) hw16[HW_BB2 + j] = f2bf(bb2_w[j]);
  for (int j = i; j < 32768; j += T) hw16[HW_CH2 + j] = f2bf(ch2_w[j]);
  for (int j = i; j < 20480; j += T) hw16[HW_CTP + j] = f2bf(ctp_w[j]);
}

// comb rows 128..255 = position encoding (batch-independent, replicated), bf16
__global__ __launch_bounds__(256) void pos_fill_kernel(const float* __restrict__ pos_w,
                                                       const float* __restrict__ pos_b,
                                                       unsigned short* __restrict__ comb16){
  int idx = blockIdx.x * 256 + threadIdx.x;      // c*4096 + m, c in 0..127
  int c = idx >> 12;
  int m = idx & 4095;
  int row = m >> 6, col = m & 63;
  float y = -1.f + 2.f * (float)row / 63.f;
  float x = -1.f + 2.f * (float)col / 63.f;
  unsigned short v = f2bf(pos_w[c*2] * y + pos_w[c*2+1] * x + pos_b[c]);
  #pragma unroll
  for (int b = 0; b < BB; b++)
    comb16[((size_t)(b*HIDC + 128 + c))*MM + m] = v;
}

// comb rows 0..127 = relu(bn(fp_w[0:128] @ x + fp_b)) -> bf16. 128x128 tile, 8x8/thread.
__global__ __launch_bounds__(256) void comb_gemm_kernel(const float* __restrict__ x,
    const float* __restrict__ fp_w, const float* __restrict__ fp_b,
    const float* __restrict__ bn_g, const float* __restrict__ bn_b,
    const float* __restrict__ bn_m, const float* __restrict__ bn_v,
    unsigned short* __restrict__ comb16){
  int b = blockIdx.z;
  int col0 = blockIdx.x * 128;
  const float* xb = x + (size_t)b * CIN * MM;
  unsigned short* cb = comb16 + (size_t)b * HIDC * MM;
  __shared__ float as[16][132];
  __shared__ float bs[16][128];
  int tx = threadIdx.x, ty = threadIdx.y;
  int tid = ty * 16 + tx;
  float acc[8][8] = {};
  for (int k0 = 0; k0 < CIN; k0 += 16){
    {
      int r = tid >> 1, kh = (tid & 1) * 8;
      float4 v0 = *(const float4*)&fp_w[(size_t)r * CIN + k0 + kh];
      float4 v1 = *(const float4*)&fp_w[(size_t)r * CIN + k0 + kh + 4];
      as[kh+0][r] = v0.x; as[kh+1][r] = v0.y; as[kh+2][r] = v0.z; as[kh+3][r] = v0.w;
      as[kh+4][r] = v1.x; as[kh+5][r] = v1.y; as[kh+6][r] = v1.z; as[kh+7][r] = v1.w;
    }
    {
      int kk = tid >> 4, j = (tid & 15) * 8;
      *(float4*)&bs[kk][j]     = *(const float4*)&xb[(size_t)(k0 + kk) * MM + col0 + j];
      *(float4*)&bs[kk][j + 4] = *(const float4*)&xb[(size_t)(k0 + kk) * MM + col0 + j + 4];
    }
    __syncthreads();
    #pragma unroll
    for (int kk = 0; kk < 16; kk++){
      float4 a0 = *(const float4*)&as[kk][ty*8];
      float4 a1 = *(const float4*)&as[kk][ty*8 + 4];
      float4 b0 = *(const float4*)&bs[kk][tx*8];
      float4 b1 = *(const float4*)&bs[kk][tx*8 + 4];
      float av[8] = {a0.x,a0.y,a0.z,a0.w,a1.x,a1.y,a1.z,a1.w};
      float bv[8] = {b0.x,b0.y,b0.z,b0.w,b1.x,b1.y,b1.z,b1.w};
      #pragma unroll
      for (int i = 0; i < 8; i++)
        #pragma unroll
        for (int j = 0; j < 8; j++)
          acc[i][j] += av[i] * bv[j];
    }
    __syncthreads();
  }
  #pragma unroll
  for (int i = 0; i < 8; i++){
    int r = ty*8 + i;
    float sc = rsqrtf(bn_v[r] + 1e-5f);
    float bias = fp_b[r], mu = bn_m[r], g = bn_g[r], bt = bn_b[r];
    ushort4 o0, o1;
    float v;
    v = fmaxf((acc[i][0] + bias - mu) * sc * g + bt, 0.f); o0.x = f2bf(v);
    v = fmaxf((acc[i][1] + bias - mu) * sc * g + bt, 0.f); o0.y = f2bf(v);
    v = fmaxf((acc[i][2] + bias - mu) * sc * g + bt, 0.f); o0.z = f2bf(v);
    v = fmaxf((acc[i][3] + bias - mu) * sc * g + bt, 0.f); o0.w = f2bf(v);
    v = fmaxf((acc[i][4] + bias - mu) * sc * g + bt, 0.f); o1.x = f2bf(v);
    v = fmaxf((acc[i][5] + bias - mu) * sc * g + bt, 0.f); o1.y = f2bf(v);
    v = fmaxf((acc[i][6] + bias - mu) * sc * g + bt, 0.f); o1.z = f2bf(v);
    v = fmaxf((acc[i][7] + bias - mu) * sc * g + bt, 0.f); o1.w = f2bf(v);
    *(ushort4*)&cb[(size_t)r * MM + col0 + tx*8]     = o0;
    *(ushort4*)&cb[(size_t)r * MM + col0 + tx*8 + 4] = o1;
  }
}

// keysT[m][d] = (key_w(64x256) @ comb(256x4096) + key_b)^T -> bf16 m-major (64 contiguous d).
// 64x128 tile, 4x8/thread; transposed epilogue stores ushort4 (4 consecutive d) per m.
__global__ __launch_bounds__(256) void keys_gemm_kernel(const unsigned short* __restrict__ comb16,
    const float* __restrict__ key_w, const float* __restrict__ key_b,
    unsigned short* __restrict__ keysT){
  int b = blockIdx.z;
  int col0 = blockIdx.x * 128;
  const unsigned short* cb = comb16 + (size_t)b * HIDC * MM;
  unsigned short* kbT = keysT + (size_t)b * MM * 64;
  __shared__ float as[16][68];
  __shared__ float bs[16][132];
  int tx = threadIdx.x, ty = threadIdx.y;
  int tid = ty * 16 + tx;
  float acc[4][8] = {};
  for (int k0 = 0; k0 < HIDC; k0 += 16){
    {
      int r = tid >> 2, kh = (tid & 3) * 4;
      float4 v0 = *(const float4*)&key_w[(size_t)r * HIDC + k0 + kh];
      as[kh+0][r] = v0.x; as[kh+1][r] = v0.y; as[kh+2][r] = v0.z; as[kh+3][r] = v0.w;
    }
    {
      int kk = tid >> 4, j = (tid & 15) * 8;
      float4 f0 = ld_bf4(&cb[(size_t)(k0 + kk) * MM + col0 + j]);
      float4 f1 = ld_bf4(&cb[(size_t)(k0 + kk) * MM + col0 + j + 4]);
      *(float4*)&bs[kk][j]     = f0;
      *(float4*)&bs[kk][j + 4] = f1;
    }
    __syncthreads();
    #pragma unroll
    for (int kk = 0; kk < 16; kk++){
      float4 a0 = *(const float4*)&as[kk][ty*4];
      float4 b0 = *(const float4*)&bs[kk][tx*8];
      float4 b1 = *(const float4*)&bs[kk][tx*8 + 4];
      float av[4] = {a0.x,a0.y,a0.z,a0.w};
      float bv[8] = {b0.x,b0.y,b0.z,b0.w,b1.x,b1.y,b1.z,b1.w};
      #pragma unroll
      for (int i = 0; i < 4; i++)
        #pragma unroll
        for (int j = 0; j < 8; j++)
          acc[i][j] += av[i] * bv[j];
    }
    __syncthreads();
  }
  float kb0 = key_b[ty*4+0], kb1 = key_b[ty*4+1], kb2 = key_b[ty*4+2], kb3 = key_b[ty*4+3];
  #pragma unroll
  for (int j = 0; j < 8; j++){
    int m = col0 + tx*8 + j;
    ushort4 o;
    o.x = f2bf(acc[0][j] + kb0);
    o.y = f2bf(acc[1][j] + kb1);
    o.z = f2bf(acc[2][j] + kb2);
    o.w = f2bf(acc[3][j] + kb3);
    *(ushort4*)&kbT[(size_t)m*64 + ty*4] = o;
  }
}

// ======== fused no-P attention: MFMA logits, 2 passes ========
// Fragment layout (same as harness-verified mfma_nt_kernel below):
//   A: row = lane&15, k = (lane>>4)*8..+7  -> lanes 32..63 carry k=16..31 = zero pad
//   B: col = lane&15, k = (lane>>4)*8..+7  -> lanes 32..63 zero pad
//   D: col = lane&15, row = (lane>>4)*4 + reg

// pass 1: sums[b][h][n] = sum_m exp(q.k/4). grid (8 m-chunks, 5 n-tiles, 16 b), 256 thr.
__global__ __launch_bounds__(256) void attn_sums_kernel(
    const unsigned short* __restrict__ q16, const unsigned short* __restrict__ keysT,
    float* __restrict__ sums){
  int b = blockIdx.z, ny = blockIdx.y, mx = blockIdx.x;
  int tid = threadIdx.x, w = tid >> 6, lane = tid & 63;
  int n0 = ny * 64;
  int l15 = lane & 15, qh = lane >> 4;
  int ko = (qh & 1) * 8;
  bool lo = lane < 32;
  const unsigned short* kT = keysT + (size_t)b * MM * 64;
  int mwb = mx*512 + w*128;
  __shared__ float spart[4][NHH][64];
  short8 zz = {0,0,0,0,0,0,0,0};
  for (int h = 0; h < NHH; h++){
    short8 a[4];
    #pragma unroll
    for (int i = 0; i < 4; i++)
      a[i] = lo ? *(const short8*)&q16[(size_t)(n0 + i*16 + l15)*64 + h*16 + ko] : zz;
    floatx4 sacc[4];
    #pragma unroll
    for (int i = 0; i < 4; i++) sacc[i] = (floatx4){0.f,0.f,0.f,0.f};
    for (int ms = 0; ms < 8; ms++){
      int m = mwb + ms*16 + l15;
      short8 bf = lo ? *(const short8*)&kT[(size_t)m*64 + h*16 + ko] : zz;
      #pragma unroll
      for (int i = 0; i < 4; i++){
        floatx4 l = __builtin_amdgcn_mfma_f32_16x16x32_bf16(a[i], bf,
                        (floatx4){0.f,0.f,0.f,0.f}, 0, 0, 0);
        sacc[i][0] += __expf(l[0]); sacc[i][1] += __expf(l[1]);
        sacc[i][2] += __expf(l[2]); sacc[i][3] += __expf(l[3]);
      }
    }
    #pragma unroll
    for (int i = 0; i < 4; i++)
      #pragma unroll
      for (int reg = 0; reg < 4; reg++){
        float v = sacc[i][reg];
        v += __shfl_xor(v, 1); v += __shfl_xor(v, 2);
        v += __shfl_xor(v, 4); v += __shfl_xor(v, 8);
        if (l15 == 0) spart[w][h][i*16 + qh*4 + reg] = v;
      }
  }
  __syncthreads();
  if (tid < NHH*64){
    int h = tid >> 6, r = tid & 63, n = n0 + r;
    if (n < NQ){
      float v = spart[0][h][r] + spart[1][h][r] + spart[2][h][r] + spart[3][h][r];
      atomicAdd(&sums[((size_t)b*NHH + h)*NQ + n], v);
    }
  }
}

// pass 2: attn[b][n][m] = sum_h exp(q.k/4) * (0.25/S_bh n); writes maps fp32 + attn16 bf16
// + atomic sum-of-squares into norms. Same grid as pass 1.
__global__ __launch_bounds__(256) void attn_emit_kernel(
    const unsigned short* __restrict__ q16, const unsigned short* __restrict__ keysT,
    const float* __restrict__ sums, float* __restrict__ maps,
    unsigned short* __restrict__ attn16, float* __restrict__ norms){
  int b = blockIdx.z, ny = blockIdx.y, mx = blockIdx.x;
  int tid = threadIdx.x, w = tid >> 6, lane = tid & 63;
  int n0 = ny * 64;
  int l15 = lane & 15, qh = lane >> 4;
  int ko = (qh & 1) * 8;
  int rq = qh * 4;
  bool lo = lane < 32;
  __shared__ __align__(16) float inv_s[NHH][64];
  __shared__ float npart[4][64];
  if (tid < NHH*64){
    int h = tid >> 6, r = tid & 63, n = n0 + r;
    inv_s[h][r] = (n < NQ) ? 0.25f / sums[((size_t)b*NHH + h)*NQ + n] : 0.f;
  }
  __syncthreads();
  const unsigned short* kT = keysT + (size_t)b * MM * 64;
  int mwb = mx*512 + w*128;
  short8 zz = {0,0,0,0,0,0,0,0};
  short8 a[NHH][4];
  #pragma unroll
  for (int h = 0; h < NHH; h++)
    #pragma unroll
    for (int i = 0; i < 4; i++)
      a[h][i] = lo ? *(const short8*)&q16[(size_t)(n0 + i*16 + l15)*64 + h*16 + ko] : zz;
  floatx4 nacc[4];
  #pragma unroll
  for (int i = 0; i < 4; i++) nacc[i] = (floatx4){0.f,0.f,0.f,0.f};
  float* mb = maps + (size_t)b * NQ * MM;
  unsigned short* ab = attn16 + (size_t)b * NQ * MM;
  for (int ms = 0; ms < 8; ms++){
    int m = mwb + ms*16 + l15;
    floatx4 o[4];
    #pragma unroll
    for (int i = 0; i < 4; i++) o[i] = (floatx4){0.f,0.f,0.f,0.f};
    #pragma unroll
    for (int h = 0; h < NHH; h++){
      short8 bf = lo ? *(const short8*)&kT[(size_t)m*64 + h*16 + ko] : zz;
      #pragma unroll
      for (int i = 0; i < 4; i++){
        floatx4 l = __builtin_amdgcn_mfma_f32_16x16x32_bf16(a[h][i], bf,
                        (floatx4){0.f,0.f,0.f,0.f}, 0, 0, 0);
        floatx4 iv = *(const floatx4*)&inv_s[h][i*16 + rq];
        o[i][0] += __expf(l[0]) * iv[0];
        o[i][1] += __expf(l[1]) * iv[1];
        o[i][2] += __expf(l[2]) * iv[2];
        o[i][3] += __expf(l[3]) * iv[3];
      }
    }
    #pragma unroll
    for (int i = 0; i < 4; i++){
      nacc[i][0] += o[i][0]*o[i][0]; nacc[i][1] += o[i][1]*o[i][1];
      nacc[i][2] += o[i][2]*o[i][2]; nacc[i][3] += o[i][3]*o[i][3];
      #pragma unroll
      for (int reg = 0; reg < 4; reg++){
        int n = n0 + i*16 + rq + reg;
        if (n < NQ){
          mb[(size_t)n*MM + m] = o[i][reg];
          ab[(size_t)n*MM + m] = f2bf(o[i][reg]);
        }
      }
    }
  }
  #pragma unroll
  for (int i = 0; i < 4; i++)
    #pragma unroll
    for (int reg = 0; reg < 4; reg++){
      float v = nacc[i][reg];
      v += __shfl_xor(v, 1); v += __shfl_xor(v, 2);
      v += __shfl_xor(v, 4); v += __shfl_xor(v, 8);
      if (l15 == 0) npart[w][i*16 + rq + reg] = v;
    }
  __syncthreads();
  if (tid < 64){
    int n = n0 + tid;
    if (n < NQ){
      float v = npart[0][tid] + npart[1][tid] + npart[2][tid] + npart[3][tid];
      atomicAdd(&norms[(size_t)b*NQ + n], v);
    }
  }
}

// C = A @ B^T (+bias). bf16 NT MFMA, wave per 64x64 tile. Row clamp Mr, col clamp Nc.
// Writes fp32 C (if non-null) and/or bf16 C16 (if non-null); optional fused ReLU.
template<bool RELU>
__global__ __launch_bounds__(64) void mfma_nt_kernel(
    const unsigned short* __restrict__ A, size_t sA,
    const unsigned short* __restrict__ B, size_t sB,
    const float* __restrict__ bias,
    float* __restrict__ C, unsigned short* __restrict__ C16,
    size_t sC, int ldc, int Mr, int Nc, int K){
  int bz = blockIdx.z;
  const unsigned short* Ab = A + (size_t)bz * sA;
  const unsigned short* Bb = B + (size_t)bz * sB;
  int lane = threadIdx.x;
  int r16 = lane & 15;
  int ko  = (lane >> 4) * 8;
  const unsigned short* arow[4];
  const unsigned short* brow[4];
  #pragma unroll
  for (int i = 0; i < 4; i++){
    int m = blockIdx.y*64 + i*16 + r16;
    if (m > Mr - 1) m = Mr - 1;
    arow[i] = Ab + (size_t)m * K + ko;
    int n = blockIdx.x*64 + i*16 + r16;
    if (n > Nc - 1) n = Nc - 1;
    brow[i] = Bb + (size_t)n * K + ko;
  }
  floatx4 acc[4][4];
  #pragma unroll
  for (int i = 0; i < 4; i++)
    #pragma unroll
    for (int j = 0; j < 4; j++)
      acc[i][j] = (floatx4){0.f, 0.f, 0.f, 0.f};
  short8 a[4], bv[4], a2[4], b2[4];
  #pragma unroll
  for (int i = 0; i < 4; i++){
    a[i]  = *(const short8*)(arow[i]);
    bv[i] = *(const short8*)(brow[i]);
  }
  for (int k = 32; k < K; k += 32){
    #pragma unroll
    for (int i = 0; i < 4; i++){
      a2[i] = *(const short8*)(arow[i] + k);
      b2[i] = *(const short8*)(brow[i] + k);
    }
    #pragma unroll
    for (int i = 0; i < 4; i++)
      #pragma unroll
      for (int j = 0; j < 4; j++)
        acc[i][j] = __builtin_amdgcn_mfma_f32_16x16x32_bf16(a[i], bv[j], acc[i][j], 0, 0, 0);
    #pragma unroll
    for (int i = 0; i < 4; i++){ a[i] = a2[i]; bv[i] = b2[i]; }
  }
  #pragma unroll
  for (int i = 0; i < 4; i++)
    #pragma unroll
    for (int j = 0; j < 4; j++)
      acc[i][j] = __builtin_amdgcn_mfma_f32_16x16x32_bf16(a[i], bv[j], acc[i][j], 0, 0, 0);
  int cq = lane & 15, rq = (lane >> 4) * 4;
  #pragma unroll
  for (int j = 0; j < 4; j++){
    int cc = blockIdx.x*64 + j*16 + cq;
    if (cc >= Nc) continue;
    float bv_ = bias ? bias[cc] : 0.f;
    #pragma unroll
    for (int i = 0; i < 4; i++){
      int rbase = blockIdx.y*64 + i*16 + rq;
      #pragma unroll
      for (int reg = 0; reg < 4; reg++){
        int rr = rbase + reg;
        if (rr < Mr){
          float v = acc[i][j][reg] + bv_;
          if (RELU) v = fmaxf(v, 0.f);
          size_t o = (size_t)bz * sC + (size_t)rr * ldc + cc;
          if (C)   C[o] = v;
          if (C16) C16[o] = f2bf(v);
        }
      }
    }
  }
}

// split-K variant: fp32 atomicAdd into pre-zeroed C
__global__ __launch_bounds__(64) void mfma_nt_splitk_kernel(
    const unsigned short* __restrict__ A, size_t sA,
    const unsigned short* __restrict__ B, size_t sB,
    float* __restrict__ C, size_t sC, int ldc, int Mr, int K, int kchunk){
  int nks = K / kchunk;
  int bz = blockIdx.z / nks;
  int kz = blockIdx.z % nks;
  const unsigned short* Ab = A + (size_t)bz * sA + (size_t)kz * kchunk;
  const unsigned short* Bb = B + (size_t)bz * sB + (size_t)kz * kchunk;
  int lane = threadIdx.x;
  int r16 = lane & 15;
  int ko  = (lane >> 4) * 8;
  const unsigned short* arow[4];
  const unsigned short* brow[4];
  #pragma unroll
  for (int i = 0; i < 4; i++){
    int m = blockIdx.y*64 + i*16 + r16;
    if (m > Mr - 1) m = Mr - 1;
    arow[i] = Ab + (size_t)m * K + ko;
    int n = blockIdx.x*64 + i*16 + r16;
    brow[i] = Bb + (size_t)n * K + ko;
  }
  floatx4 acc[4][4];
  #pragma unroll
  for (int i = 0; i < 4; i++)
    #pragma unroll
    for (int j = 0; j < 4; j++)
      acc[i][j] = (floatx4){0.f, 0.f, 0.f, 0.f};
  short8 a[4], bv[4], a2[4], b2[4];
  #pragma unroll
  for (int i = 0; i < 4; i++){
    a[i]  = *(const short8*)(arow[i]);
    bv[i] = *(const short8*)(brow[i]);
  }
  for (int k = 32; k < kchunk; k += 32){
    #pragma unroll
    for (int i = 0; i < 4; i++){
      a2[i] = *(const short8*)(arow[i] + k);
      b2[i] = *(const short8*)(brow[i] + k);
    }
    #pragma unroll
    for (int i = 0; i < 4; i++)
      #pragma unroll
      for (int j = 0; j < 4; j++)
        acc[i][j] = __builtin_amdgcn_mfma_f32_16x16x32_bf16(a[i], bv[j], acc[i][j], 0, 0, 0);
    #pragma unroll
    for (int i = 0; i < 4; i++){ a[i] = a2[i]; bv[i] = b2[i]; }
  }
  #pragma unroll
  for (int i = 0; i < 4; i++)
    #pragma unroll
    for (int j = 0; j < 4; j++)
      acc[i][j] = __builtin_amdgcn_mfma_f32_16x16x32_bf16(a[i], bv[j], acc[i][j], 0, 0, 0);
  int cq = lane & 15, rq = (lane >> 4) * 4;
  #pragma unroll
  for (int j = 0; j < 4; j++){
    int cc = blockIdx.x*64 + j*16 + cq;
    #pragma unroll
    for (int i = 0; i < 4; i++){
      int rbase = blockIdx.y*64 + i*16 + rq;
      #pragma unroll
      for (int reg = 0; reg < 4; reg++){
        int rr = rbase + reg;
        if (rr < Mr)
          atomicAdd(&C[(size_t)bz * sC + (size_t)rr * ldc + cc], acc[i][j][reg]);
      }
    }
  }
}

// LayerNorm + ReLU over 256-wide rows; fp32 in, bf16 out. 4 rows/block (wave per row).
__global__ __launch_bounds__(256) void ln_relu_kernel(const float* __restrict__ zin,
    const float* __restrict__ g, const float* __restrict__ bvec,
    unsigned short* __restrict__ zout){
  int row = blockIdx.x * 4 + (threadIdx.x >> 6);
  int lane = threadIdx.x & 63;
  float4 v = *(const float4*)&zin[(size_t)row * 256 + lane * 4];
  float s = v.x + v.y + v.z + v.w;
  #pragma unroll
  for (int off = 32; off >= 1; off >>= 1) s += __shfl_xor(s, off);
  float mean = s * (1.f/256.f);
  float dx = v.x - mean, dy = v.y - mean, dz = v.z - mean, dw = v.w - mean;
  float sq = dx*dx + dy*dy + dz*dz + dw*dw;
  #pragma unroll
  for (int off = 32; off >= 1; off >>= 1) sq += __shfl_xor(sq, off);
  float inv = rsqrtf(sq * (1.f/256.f) + 1e-5f);
  float4 gv = *(const float4*)&g[lane * 4];
  float4 bb = *(const float4*)&bvec[lane * 4];
  ushort4 u;
  u.x = f2bf(fmaxf(dx*inv*gv.x + bb.x, 0.f));
  u.y = f2bf(fmaxf(dy*inv*gv.y + bb.y, 0.f));
  u.z = f2bf(fmaxf(dz*inv*gv.z + bb.z, 0.f));
  u.w = f2bf(fmaxf(dw*inv*gv.w + bb.w, 0.f));
  *(ushort4*)&zout[(size_t)row * 256 + lane * 4] = u;
}

// final tiny projections: boxes = z2bb @ bb3^T + b; scores = sigmoid(z2ch @ ch3^T + b)
__global__ __launch_bounds__(256) void head3_kernel(
    const unsigned short* __restrict__ z2bb, const unsigned short* __restrict__ z2ch,
    const float* __restrict__ bb3_w, const float* __restrict__ bb3_b,
    const float* __restrict__ ch3_w, const float* __restrict__ ch3_b,
    float* __restrict__ boxes, float* __restrict__ scores){
  int row = blockIdx.x * 4 + (threadIdx.x >> 6);
  int lane = threadIdx.x & 63;
  float zb0 = bf1(z2bb[(size_t)row*128 + 2*lane]);
  float zb1 = bf1(z2bb[(size_t)row*128 + 2*lane + 1]);
  float zc0 = bf1(z2ch[(size_t)row*128 + 2*lane]);
  float zc1 = bf1(z2ch[(size_t)row*128 + 2*lane + 1]);
  float acc[5];
  #pragma unroll
  for (int o = 0; o < 4; o++)
    acc[o] = bb3_w[o*128 + 2*lane]*zb0 + bb3_w[o*128 + 2*lane + 1]*zb1;
  acc[4] = ch3_w[2*lane]*zc0 + ch3_w[2*lane + 1]*zc1;
  #pragma unroll
  for (int o = 0; o < 5; o++){
    float v = acc[o];
    #pragma unroll
    for (int off = 32; off >= 1; off >>= 1) v += __shfl_xor(v, off);
    acc[o] = v;
  }
  if (lane == 0){
    #pragma unroll
    for (int o = 0; o < 4; o++)
      boxes[(size_t)row*4 + o] = acc[o] + bb3_b[o];
    float sv = acc[4] + ch3_b[0];
    scores[row] = 1.f / (1.f + __expf(-sv));
  }
}

// diversity: sum_m (sum_n attn[n,m]/||attn_n||)^2  (bf16 attn copy; norms holds SUM OF SQUARES)
__global__ __launch_bounds__(256) void simdiv_kernel(const unsigned short* __restrict__ attn16,
    const float* __restrict__ norms, float* __restrict__ acc){
  int b = blockIdx.y;
  int m = blockIdx.x * 256 + threadIdx.x;
  __shared__ float inv_s[NQ];
  __shared__ float red[4];
  for (int i = threadIdx.x; i < NQ; i += 256)
    inv_s[i] = 1.f / fmaxf(sqrtf(norms[(size_t)b * NQ + i]), 1e-12f);
  __syncthreads();
  const unsigned short* ab = attn16 + (size_t)b * NQ * MM;
  float S = 0.f;
  for (int n = 0; n < NQ; n++)
    S += bf1(ab[(size_t)n * MM + m]) * inv_s[n];
  float p = S * S;
  #pragma unroll
  for (int off = 32; off >= 1; off >>= 1) p += __shfl_xor(p, off);
  int w = threadIdx.x >> 6, lane = threadIdx.x & 63;
  if (lane == 0) red[w] = p;
  __syncthreads();
  if (threadIdx.x == 0) atomicAdd(acc, red[0] + red[1] + red[2] + red[3]);
}

__global__ void finalize_kernel(const float* __restrict__ acc, float* __restrict__ out_div){
  out_div[0] = (acc[0] - (float)(BB * NQ)) / (float)(NQ * (NQ - 1)) * 0.1f;
}

extern "C" void kernel_launch(void* const* d_in, const int* in_sizes, int n_in,
                              void* d_out, int out_size, void* d_ws, size_t ws_size,
                              hipStream_t stream){
  const float* x      = (const float*)d_in[0];
  const float* ss     = (const float*)d_in[1];
  const float* pos_w  = (const float*)d_in[2];
  const float* pos_b  = (const float*)d_in[3];
  const float* fp_w   = (const float*)d_in[4];
  const float* fp_b   = (const float*)d_in[5];
  const float* bn_g   = (const float*)d_in[6];
  const float* bn_b   = (const float*)d_in[7];
  const float* bn_m   = (const float*)d_in[8];
  const float* bn_v   = (const float*)d_in[9];
  const float* key_w  = (const float*)d_in[10];
  const float* key_b  = (const float*)d_in[11];
  const float* val_w  = (const float*)d_in[12];
  const float* val_b  = (const float*)d_in[13];
  const float* ctp_w  = (const float*)d_in[14];
  const float* ctp_b  = (const float*)d_in[15];
  const float* bb1_w  = (const float*)d_in[16];
  const float* bb1_b  = (const float*)d_in[17];
  const float* bbln_g = (const float*)d_in[18];
  const float* bbln_b = (const float*)d_in[19];
  const float* bb2_w  = (const float*)d_in[20];
  const float* bb2_b  = (const float*)d_in[21];
  const float* bb3_w  = (const float*)d_in[22];
  const float* bb3_b  = (const float*)d_in[23];
  const float* ch1_w  = (const float*)d_in[24];
  const float* ch1_b  = (const float*)d_in[25];
  const float* chln_g = (const float*)d_in[26];
  const float* chln_b = (const float*)d_in[27];
  const float* ch2_w  = (const float*)d_in[28];
  const float* ch2_b  = (const float*)d_in[29];
  const float* ch3_w  = (const float*)d_in[30];
  const float* ch3_b  = (const float*)d_in[31];

  float* out    = (float*)d_out;
  float* boxes  = out + OFF_BOXES;
  float* scores = out + OFF_SCORES;
  float* cls    = out + OFF_CLS;
  float* maps   = out + OFF_MAPS;
  float* divp   = out + OFF_DIV;
  float* sfout  = out + OFF_SF;

  float* ws = (float*)d_ws;
  unsigned short* comb16 = (unsigned short*)(ws + WS_COMB16);
  unsigned short* keysT  = (unsigned short*)(ws + WS_KEYS16);
  unsigned short* attn16 = (unsigned short*)(ws + WS_ATTN16);
  float*          t32    = ws + WS_T32;
  unsigned short* t16    = (unsigned short*)(ws + WS_T16);
  unsigned short* valw16 = (unsigned short*)(ws + WS_VALW16);
  float* sums  = ws + WS_SUMS;
  float* norms = ws + WS_NORM;
  float* dacc  = ws + WS_ACC;
  unsigned short* sf16   = (unsigned short*)(ws + HP_SF16);
  float*          z1pre  = ws + HP_Z1PRE;
  unsigned short* z1_16  = (unsigned short*)(ws + HP_Z1_16);
  unsigned short* z2bb16 = (unsigned short*)(ws + HP_Z2BB);
  unsigned short* z2ch16 = (unsigned short*)(ws + HP_Z2CH);
  unsigned short* hw16   = (unsigned short*)(ws + HP_HW);
  unsigned short* q16    = (unsigned short*)(ws + WS_Q16);

  zero_kernel<<<1, 1, 0, stream>>>(dacc);
  zero4_kernel<<<1200, 256, 0, stream>>>((float4*)t32, 307200);
  // sums (19200 fl) and norms (4800 fl) are contiguous -> one zeroing pass
  zero4_kernel<<<24, 256, 0, stream>>>((float4*)sums, 6000);
  castq_kernel<<<80, 256, 0, stream>>>(ss, q16);
  pos_fill_kernel<<<2048, 256, 0, stream>>>(pos_w, pos_b, comb16);
  comb_gemm_kernel<<<dim3(32,1,16), dim3(16,16), 0, stream>>>(x, fp_w, fp_b, bn_g, bn_b, bn_m, bn_v, comb16);
  keys_gemm_kernel<<<dim3(32,1,16), dim3(16,16), 0, stream>>>(comb16, key_w, key_b, keysT);

  // fused no-P attention: MFMA logits, 2 passes over L2-resident keysT
  attn_sums_kernel<<<dim3(8,5,16), 256, 0, stream>>>(q16, keysT, sums);
  attn_emit_kernel<<<dim3(8,5,16), 256, 0, stream>>>(q16, keysT, sums, maps, attn16, norms);

  // t32 = attn @ comb^T  (split-K x4, fp32 atomic accumulate)
  mfma_nt_splitk_kernel<<<dim3(4,5,BB*4), 64, 0, stream>>>(
      attn16, (size_t)NQ*MM, comb16, (size_t)HIDC*MM,
      t32, (size_t)NQ*HIDC, HIDC, NQ, MM, MM/4);
  cast4_bf16_kernel<<<1200, 256, 0, stream>>>(t32, t16, 307200);
  cast_heads_kernel<<<256, 256, 0, stream>>>(val_w, bb1_w, ch1_w, bb2_w, ch2_w, ctp_w, valw16, hw16);
  // sf = t @ val_w^T + val_b  (fp32 into d_out, bf16 into sf16)
  mfma_nt_kernel<false><<<dim3(4,5,BB), 64, 0, stream>>>(
      t16, (size_t)NQ*HIDC, valw16, 0, val_b,
      sfout, sf16, (size_t)NQ*HIDC, HIDC, NQ, HIDC, HIDC);

  // ---- boxes head ----
  mfma_nt_kernel<false><<<dim3(4,75,1), 64, 0, stream>>>(
      sf16, 0, hw16 + HW_BB1, 0, bb1_b, z1pre, nullptr, 0, 256, 4800, 256, 256);
  ln_relu_kernel<<<1200, 256, 0, stream>>>(z1pre, bbln_g, bbln_b, z1_16);
  mfma_nt_kernel<true><<<dim3(2,75,1), 64, 0, stream>>>(
      z1_16, 0, hw16 + HW_BB2, 0, bb2_b, nullptr, z2bb16, 0, 128, 4800, 128, 256);
  // ---- scores head ----
  mfma_nt_kernel<false><<<dim3(4,75,1), 64, 0, stream>>>(
      sf16, 0, hw16 + HW_CH1, 0, ch1_b, z1pre, nullptr, 0, 256, 4800, 256, 256);
  ln_relu_kernel<<<1200, 256, 0, stream>>>(z1pre, chln_g, chln_b, z1_16);
  mfma_nt_kernel<true><<<dim3(2,75,1), 64, 0, stream>>>(
      z1_16, 0, hw16 + HW_CH2, 0, ch2_b, nullptr, z2ch16, 0, 128, 4800, 128, 256);
  // ---- finals + cls ----
  head3_kernel<<<1200, 256, 0, stream>>>(z2bb16, z2ch16, bb3_w, bb3_b, ch3_w, ch3_b, boxes, scores);
  mfma_nt_kernel<false><<<dim3(2,75,1), 64, 0, stream>>>(
      sf16, 0, hw16 + HW_CTP, 0, ctp_b, cls, nullptr, 0, 80, 4800, 80, 256);

  simdiv_kernel<<<dim3(16,16), 256, 0, stream>>>(attn16, norms, dacc);
  finalize_kernel<<<1, 1, 0, stream>>>(dacc, divp);
}